// Round 18
// baseline (137.524 us; speedup 1.0000x reference)
//
#include <hip/hip_runtime.h>
#include <hip/hip_bf16.h>
#include <cstdint>
#include <cstddef>

#define HW   1024   // H*W tokens
#define NC   512    // channels
#define NB   16     // batch
#define EPSV 1e-5f

typedef __hip_bfloat16 bf16;
typedef __attribute__((ext_vector_type(8))) __bf16 bf16x8;
typedef __attribute__((ext_vector_type(4))) float f32x4;

__device__ __forceinline__ void gload16(const void* g, void* l) {
  __builtin_amdgcn_global_load_lds(
      (const __attribute__((address_space(1))) uint32_t*)g,
      (__attribute__((address_space(3))) uint32_t*)l, 16, 0, 0);
}

// ---------------- weight fp32 -> bf16 convert ----------------
// wib: linear [1536][512]. wob: FRAGMENT layout [chh 32][kc 16][co_lo 16][64B]
__global__ __launch_bounds__(256) void cvt_w_kernel(
    const float* __restrict__ wi, const float* __restrict__ wo,
    bf16* __restrict__ wib, char* __restrict__ wobf) {
  int i = blockIdx.x * 256 + threadIdx.x;
  if (i < 196608) {
    float4 v = ((const float4*)wi)[i];
    union { bf16 h[4]; uint2 u; } p;
    p.h[0] = __float2bfloat16(v.x); p.h[1] = __float2bfloat16(v.y);
    p.h[2] = __float2bfloat16(v.z); p.h[3] = __float2bfloat16(v.w);
    *(uint2*)&wib[(size_t)i * 4] = p.u;
  } else {
    int j = i - 196608;                   // 65536 float4s of w_out [512][512]
    float4 v = ((const float4*)wo)[j];
    int elem = j * 4;
    int co = elem >> 9, c = elem & 511;   // 4 consecutive c
    union { bf16 h[4]; uint2 u; } p;
    p.h[0] = __float2bfloat16(v.x); p.h[1] = __float2bfloat16(v.y);
    p.h[2] = __float2bfloat16(v.z); p.h[3] = __float2bfloat16(v.w);
    int chh = co >> 4, col_ = co & 15, kc = c >> 5, cc = c & 31;
    *(uint2*)(wobf + (((chh * 16 + kc) << 10) + col_ * 64 + cc * 2)) = p.u;
  }
}

// ---------------- GroupNorm -> xn token-major bf16 [b][hw][c] ----------------
__global__ __launch_bounds__(256) void gn_kernel(
    const float* __restrict__ x, const float* __restrict__ gamma,
    const float* __restrict__ beta, bf16* __restrict__ xn) {
  int blk = blockIdx.x;
  int b = blk >> 5, g = blk & 31;
  size_t base = ((size_t)(b * NC + g * 16)) * HW;
  const float4* src4 = (const float4*)(x + base);
  int t = threadIdx.x;
  float s = 0.f, ss = 0.f;
  float4 v[16];
#pragma unroll
  for (int i = 0; i < 16; ++i) {
    v[i] = src4[t + i * 256];
    s  += v[i].x + v[i].y + v[i].z + v[i].w;
    ss += v[i].x * v[i].x + v[i].y * v[i].y + v[i].z * v[i].z + v[i].w * v[i].w;
  }
  __shared__ float red[256];
  red[t] = s; __syncthreads();
  for (int o = 128; o > 0; o >>= 1) { if (t < o) red[t] += red[t + o]; __syncthreads(); }
  float mean = red[0] * (1.f / 16384.f);
  __syncthreads();
  red[t] = ss; __syncthreads();
  for (int o = 128; o > 0; o >>= 1) { if (t < o) red[t] += red[t + o]; __syncthreads(); }
  float var = red[0] * (1.f / 16384.f) - mean * mean;
  float rstd = rsqrtf(var + EPSV);

  __shared__ bf16 sm[16][1032];
#pragma unroll
  for (int i = 0; i < 16; ++i) {
    int idx = t + i * 256;
    int c = idx >> 8;
    int hw4 = (idx & 255) * 4;
    float gm = gamma[g * 16 + c], bt = beta[g * 16 + c];
    union { bf16 h[4]; uint2 u; } p;
    p.h[0] = __float2bfloat16((v[i].x - mean) * rstd * gm + bt);
    p.h[1] = __float2bfloat16((v[i].y - mean) * rstd * gm + bt);
    p.h[2] = __float2bfloat16((v[i].z - mean) * rstd * gm + bt);
    p.h[3] = __float2bfloat16((v[i].w - mean) * rstd * gm + bt);
    *(uint2*)&sm[c][hw4] = p.u;
  }
  __syncthreads();
  bf16* dst = xn + (size_t)b * HW * NC + g * 16;
#pragma unroll
  for (int it = 0; it < 8; ++it) {
    int u = it * 256 + t;
    int hw = u >> 1;
    int c8 = (u & 1) * 8;
    union { bf16 h[8]; uint4 q; } p;
#pragma unroll
    for (int j = 0; j < 8; ++j) p.h[j] = sm[c8 + j][hw];
    *(uint4*)&dst[(size_t)hw * NC + c8] = p.q;
  }
}

// ---------------- merged QKV projection GEMM (one launch) ----------------
// C[M=1536][N=1024tok] = wib[1536][512] * xn^T, store per m0-range:
//   m0<512: qtok [tok][512] transposed;  <1024: K-frag [jflat 64][kw 16][1KB];
//   else:   V-frag [tile 8][chh 32][ks 4][1KB]. Block-uniform dispatch.
__global__ __launch_bounds__(256) void qkv_gemm(
    const bf16* __restrict__ wib, const bf16* __restrict__ xn,
    const float* __restrict__ bias,
    bf16* __restrict__ qtok, char* __restrict__ kfrag, char* __restrict__ vfrag) {
  __shared__ bf16 sT[2][128][32];
  int z = blockIdx.z;
  const bf16* Bb = xn + (size_t)z * (512 * 1024);
  int n0 = blockIdx.x * 128, m0 = blockIdx.y * 128;
  int t = threadIdx.x;
  int l = t & 63, w = t >> 6;
  int wm = w >> 1, wn = w & 1;

  int srow = t >> 2;
  int scol = (t & 3) * 8;

  f32x4 acc[4][4] = {};

  const bf16* ga0 = wib + (size_t)(m0 + srow) * 512 + scol;
  const bf16* gb0 = Bb + (size_t)(n0 + srow) * 512 + scol;

  for (int k0 = 0; k0 < 512; k0 += 32) {
    gload16(ga0 + k0, &sT[0][srow][scol]);
    gload16(ga0 + (size_t)64 * 512 + k0, &sT[0][64 + srow][scol]);
    gload16(gb0 + k0, &sT[1][srow][scol]);
    gload16(gb0 + (size_t)64 * 512 + k0, &sT[1][64 + srow][scol]);
    __syncthreads();
    bf16x8 af[4], bfr[4];
    int kc = (l >> 4) * 8;
    int ra = wm * 64 + (l & 15);
    int rb = wn * 64 + (l & 15);
#pragma unroll
    for (int i = 0; i < 4; ++i) {
      af[i]  = *(const bf16x8*)&sT[0][ra + i * 16][kc];
      bfr[i] = *(const bf16x8*)&sT[1][rb + i * 16][kc];
    }
#pragma unroll
    for (int i = 0; i < 4; ++i)
#pragma unroll
      for (int j = 0; j < 4; ++j)
        acc[i][j] = __builtin_amdgcn_mfma_f32_16x16x32_bf16(af[i], bfr[j], acc[i][j], 0, 0, 0);
    __syncthreads();
  }

  int rbase = (l >> 4) * 4;
#pragma unroll
  for (int i = 0; i < 4; ++i) {
    int row = m0 + wm * 64 + i * 16 + rbase;    // 0..1535
    float4 bv = *(const float4*)&bias[row];
    float bb[4] = {bv.x, bv.y, bv.z, bv.w};
#pragma unroll
    for (int j = 0; j < 4; ++j) {
      int col = n0 + wn * 64 + j * 16 + (l & 15);
      if (m0 < 512) {
        bf16* C = qtok + (size_t)z * 524288;
        union { bf16 h[4]; uint2 u; } p;
#pragma unroll
        for (int r = 0; r < 4; ++r) p.h[r] = __float2bfloat16(acc[i][j][r] + bb[r]);
        *(uint2*)&C[(size_t)col * 512 + row] = p.u;
      } else if (m0 < 1024) {
        char* C = kfrag + (size_t)z * 1048576;
        int rk = row - 512;
        int jflat = col >> 4, j_lo = col & 15;
        int kw = rk >> 5, cc = rk & 31;
        union { bf16 h[4]; uint2 u; } p;
#pragma unroll
        for (int r = 0; r < 4; ++r) p.h[r] = __float2bfloat16(acc[i][j][r] + bb[r]);
        *(uint2*)(C + (((size_t)(jflat * 16 + kw)) << 10) + j_lo * 64 + cc * 2) = p.u;
      } else {
        char* C = vfrag + (size_t)z * 1048576;
        int rv = row - 1024;
        int tile = col >> 7, jj = col & 127;
        int ks = jj >> 5, jc = jj & 31;
#pragma unroll
        for (int r = 0; r < 4; ++r) {
          int ch = rv + r;
          int chh = ch >> 4, chl = ch & 15;
          *(bf16*)(C + (((tile * 32 + chh) * 4 + ks) << 10)
                     + chl * 64 + jc * 2) = __float2bfloat16(acc[i][j][r] + bb[r]);
        }
      }
    }
  }
}

// ---------------- fused flash attention + out-projection ----------------
// grid: 256 wg (QBLK=64), 512 threads (8 waves). KVBLK=256, 4 KV tiles.
// Wave owns 32 j (2 j-groups) per tile. K,V,W direct from L2 in fragment-
// linear layout. LDS 96KB: Qs 64KB + Ps 32KB. T5: s_setprio(1) around the
// MFMA clusters (waves diverge between barriers: QK-MFMA vs exp/pack).
__global__ __launch_bounds__(512, 1) void flash_kernel(
    const bf16* __restrict__ qtok, const bf16* __restrict__ kfrag,
    const bf16* __restrict__ vfrag, const bf16* __restrict__ wfrag,
    const float* __restrict__ b_out, const float* __restrict__ x,
    float* __restrict__ out) {
  __shared__ char lds[98304];
  char* Qs = lds;                        // 64KB: [ni 4][ks 16][i_lo 16][64B]
  char* Ps = lds + 65536;                // 32KB: [ni 4][js 8][i_lo 16][64B]
  float* redl = (float*)(lds + 65536);   // epilogue overlay (2KB, Ps dead)

  int id = blockIdx.x;
  int xcd = id & 7, rest = id >> 3;
  int q = rest & 15, bh = rest >> 4;
  int b = xcd + bh * 8;                  // batch -> fixed XCD (K/V L2 locality)
  int i0 = q * 64;

  const char* qC = (const char*)qtok + (size_t)b * 1048576;   // [1024 tok][512]
  const char* kC = (const char*)kfrag + (size_t)b * 1048576;  // frag layout
  const char* vC = (const char*)vfrag + (size_t)b * 1048576;  // frag layout
  const char* wC = (const char*)wfrag;                        // frag layout

  int t = threadIdx.x, l = t & 63, w = t >> 6;
  int l15 = l & 15, lq = l >> 4;
  int fofs = l15 * 64 + lq * 16;         // fragment byte offset (row l15, lq)
  int chb = w * 64;

  // ---- prologue: stage Q subtiled
#pragma unroll
  for (int it = 0; it < 8; ++it) {
    int A = it * 8192 + t * 16;
    int ih2 = A >> 14, ks = (A >> 10) & 15, ilo = (A >> 6) & 15, cb = A & 63;
    gload16(qC + (size_t)(i0 + ih2 * 16 + ilo) * 1024 + ks * 64 + cb, Qs + A);
  }

  float lacc[4] = {0.f, 0.f, 0.f, 0.f};
  f32x4 o[4][4] = {};                        // [mi: ch frag][ni: i frag]
  const float scl = 0.044194173824159216f;   // 1/sqrt(512)

  __syncthreads();   // Q staged

  for (int tile = 0; tile < 4; ++tile) {
    // V prefetch half A: js 0..3 (f = tile*8+js), consumed after P barrier
    bf16x8 vfA[4][4];
#pragma unroll
    for (int js = 0; js < 4; ++js)
#pragma unroll
      for (int mi = 0; mi < 4; ++mi) {
        int f = tile * 8 + js;
        vfA[js][mi] = *(const bf16x8*)(vC
            + (((size_t)(((f >> 2) * 32 + (w * 4 + mi)) * 4 + (f & 3))) << 10) + fofs);
      }
    // ---- QK^T: S^T[32 j][64 i] per wave (2 j-groups share each Q read)
    f32x4 s0[4] = {}, s1[4] = {};
    __builtin_amdgcn_s_setprio(1);
#pragma unroll
    for (int kw = 0; kw < 16; ++kw) {
      int jf0 = tile * 16 + w * 2;
      bf16x8 kf0 = *(const bf16x8*)(kC + (((size_t)(jf0 * 16 + kw)) << 10) + fofs);
      bf16x8 kf1 = *(const bf16x8*)(kC + (((size_t)((jf0 + 1) * 16 + kw)) << 10) + fofs);
#pragma unroll
      for (int ni = 0; ni < 4; ++ni) {
        bf16x8 qf = *(const bf16x8*)(Qs + ni * 16384 + kw * 1024 + fofs);
        s0[ni] = __builtin_amdgcn_mfma_f32_16x16x32_bf16(kf0, qf, s0[ni], 0, 0, 0);
        s1[ni] = __builtin_amdgcn_mfma_f32_16x16x32_bf16(kf1, qf, s1[ni], 0, 0, 0);
      }
    }
    __builtin_amdgcn_s_setprio(0);
    // ---- P = exp(s*scl), pack into Ps[ni][js=w]; j_in_32 = jg*16 + lq*4 + r
#pragma unroll
    for (int ni = 0; ni < 4; ++ni) {
#pragma unroll
      for (int jg = 0; jg < 2; ++jg) {
        const f32x4& sv = jg ? s1[ni] : s0[ni];
        float p0 = __expf(sv[0] * scl);
        float p1 = __expf(sv[1] * scl);
        float p2 = __expf(sv[2] * scl);
        float p3 = __expf(sv[3] * scl);
        lacc[ni] += p0 + p1 + p2 + p3;
        union { bf16 h[4]; uint64_t u; } pk;
        pk.h[0] = __float2bfloat16(p0); pk.h[1] = __float2bfloat16(p1);
        pk.h[2] = __float2bfloat16(p2); pk.h[3] = __float2bfloat16(p3);
        *(uint64_t*)(Ps + ni * 8192 + w * 1024 + l15 * 64 + jg * 32 + lq * 8) = pk.u;
      }
    }
    __syncthreads();   // P ready
    // V prefetch half B: js 4..7 (loads fly under PV of half A)
    bf16x8 vfB[4][4];
#pragma unroll
    for (int js = 0; js < 4; ++js)
#pragma unroll
      for (int mi = 0; mi < 4; ++mi) {
        int f = tile * 8 + 4 + js;
        vfB[js][mi] = *(const bf16x8*)(vC
            + (((size_t)(((f >> 2) * 32 + (w * 4 + mi)) * 4 + (f & 3))) << 10) + fofs);
      }
    // ---- PV: O^T[64 ch][64 i] += V^T x P
    __builtin_amdgcn_s_setprio(1);
#pragma unroll
    for (int js = 0; js < 4; ++js)
#pragma unroll
      for (int ni = 0; ni < 4; ++ni) {
        bf16x8 pf = *(const bf16x8*)(Ps + ni * 8192 + js * 1024 + fofs);
#pragma unroll
        for (int mi = 0; mi < 4; ++mi)
          o[mi][ni] = __builtin_amdgcn_mfma_f32_16x16x32_bf16(vfA[js][mi], pf, o[mi][ni], 0, 0, 0);
      }
#pragma unroll
    for (int js = 0; js < 4; ++js)
#pragma unroll
      for (int ni = 0; ni < 4; ++ni) {
        bf16x8 pf = *(const bf16x8*)(Ps + ni * 8192 + (4 + js) * 1024 + fofs);
#pragma unroll
        for (int mi = 0; mi < 4; ++mi)
          o[mi][ni] = __builtin_amdgcn_mfma_f32_16x16x32_bf16(vfB[js][mi], pf, o[mi][ni], 0, 0, 0);
      }
    __builtin_amdgcn_s_setprio(0);
    __syncthreads();   // PV done -> Ps free for next tile
  }

  // ---- row-sum combine (redl overlays dead Ps)
#pragma unroll
  for (int ni = 0; ni < 4; ++ni) {
    float v = lacc[ni];
    v += __shfl_xor(v, 16);
    v += __shfl_xor(v, 32);
    if (l < 16) redl[w * 64 + ni * 16 + l] = v;
  }
  __syncthreads();
  float linv[4];
#pragma unroll
  for (int ni = 0; ni < 4; ++ni) {
    int i = ni * 16 + l15;
    float v = redl[i];
#pragma unroll
    for (int w2 = 1; w2 < 8; ++w2) v += redl[w2 * 64 + i];
    linv[ni] = 1.f / v;
  }
  // normalized O -> ao_lds subtiled [ni 4][kc 16][i_lo 16][64B] over dead Qs
#pragma unroll
  for (int mi = 0; mi < 4; ++mi)
#pragma unroll
    for (int ni = 0; ni < 4; ++ni) {
      union { bf16 h[4]; uint64_t u; } pk;
#pragma unroll
      for (int r = 0; r < 4; ++r)
        pk.h[r] = __float2bfloat16(o[mi][ni][r] * linv[ni]);
      int dst = ni * 16384 + (w * 2 + (mi >> 1)) * 1024 + l15 * 64
              + (mi & 1) * 32 + lq * 8;
      *(uint64_t*)(Qs + dst) = pk.u;
    }
  __syncthreads();  // ao_lds ready

  // ---- out-projection: W fragments direct from L2; no barriers in loop
  f32x4 acc2[4][4] = {};
#pragma unroll
  for (int kc = 0; kc < 16; ++kc) {
    bf16x8 wf[4];
#pragma unroll
    for (int mi = 0; mi < 4; ++mi)
      wf[mi] = *(const bf16x8*)(wC + (((size_t)(w * 4 + mi) * 16 + kc) << 10) + fofs);
    __builtin_amdgcn_s_setprio(1);
#pragma unroll
    for (int ni = 0; ni < 4; ++ni) {
      bf16x8 pf = *(const bf16x8*)(Qs + ni * 16384 + kc * 1024 + fofs);
#pragma unroll
      for (int mi = 0; mi < 4; ++mi)
        acc2[mi][ni] = __builtin_amdgcn_mfma_f32_16x16x32_bf16(wf[mi], pf, acc2[mi][ni], 0, 0, 0);
    }
    __builtin_amdgcn_s_setprio(0);
  }

  // epilogue: + bias + residual, store fp32 out[b][co][i0+i]
  const float* xb = x + (size_t)b * 524288;
  float* ob = out + (size_t)b * 524288;
#pragma unroll
  for (int mi = 0; mi < 4; ++mi) {
    int cbase = chb + mi * 16 + lq * 4;
    float4 bv = *(const float4*)&b_out[cbase];
    float bb[4] = {bv.x, bv.y, bv.z, bv.w};
#pragma unroll
    for (int ni = 0; ni < 4; ++ni) {
      int i = i0 + ni * 16 + l15;
#pragma unroll
      for (int r = 0; r < 4; ++r) {
        size_t off = (size_t)(cbase + r) * 1024 + i;
        ob[off] = acc2[mi][ni][r] + bb[r] + xb[off];
      }
    }
  }
}

extern "C" void kernel_launch(void* const* d_in, const int* in_sizes, int n_in,
                              void* d_out, int out_size, void* d_ws, size_t ws_size,
                              hipStream_t stream) {
  const float* x     = (const float*)d_in[0];
  const float* gamma = (const float*)d_in[1];
  const float* beta  = (const float*)d_in[2];
  const float* w_in  = (const float*)d_in[3];
  const float* b_in  = (const float*)d_in[4];
  const float* w_out = (const float*)d_in[5];
  const float* b_out = (const float*)d_in[6];
  float* out = (float*)d_out;

  char* w = (char*)d_ws;
  bf16* xn    = (bf16*)w;                              // 16 MB token-major
  bf16* qtok  = (bf16*)(w + ((size_t)16 << 20));       // 16 MB [b][tok][512]
  bf16* kfrag = (bf16*)(w + ((size_t)32 << 20));       // 16 MB fragment layout
  bf16* vfrag = (bf16*)(w + ((size_t)48 << 20));       // 16 MB fragment layout
  bf16* wib   = (bf16*)(w + ((size_t)64 << 20));       // 1.5 MB
  char* wobf  = (char*)(w + ((size_t)64 << 20) + ((size_t)3 << 19));  // 0.5 MB

  cvt_w_kernel<<<1024, 256, 0, stream>>>(w_in, w_out, wib, wobf);
  gn_kernel<<<NB * 32, 256, 0, stream>>>(x, gamma, beta, xn);

  // merged q/k/v projection: one launch, store-mode by m0 range
  qkv_gemm<<<dim3(8, 12, NB), 256, 0, stream>>>(
      wib, xn, b_in, qtok, (char*)kfrag, (char*)vfrag);

  // fused attention + out projection + residual
  flash_kernel<<<256, 512, 0, stream>>>(qtok, kfrag, vfrag, (const bf16*)wobf,
                                        b_out, x, out);
}

// Round 19
// 128.418 us; speedup vs baseline: 1.0709x; 1.0709x over previous
//
#include <hip/hip_runtime.h>
#include <hip/hip_bf16.h>
#include <cstdint>
#include <cstddef>

#define HW   1024   // H*W tokens
#define NC   512    // channels
#define NB   16     // batch
#define EPSV 1e-5f

typedef __hip_bfloat16 bf16;
typedef __attribute__((ext_vector_type(8))) __bf16 bf16x8;
typedef __attribute__((ext_vector_type(4))) float f32x4;

__device__ __forceinline__ void gload16(const void* g, void* l) {
  __builtin_amdgcn_global_load_lds(
      (const __attribute__((address_space(1))) uint32_t*)g,
      (__attribute__((address_space(3))) uint32_t*)l, 16, 0, 0);
}

// ---------------- weight fp32 -> bf16 convert ----------------
// wib: linear [1536][512]. wob: FRAGMENT layout [chh 32][kc 16][co_lo 16][64B]
__global__ __launch_bounds__(256) void cvt_w_kernel(
    const float* __restrict__ wi, const float* __restrict__ wo,
    bf16* __restrict__ wib, char* __restrict__ wobf) {
  int i = blockIdx.x * 256 + threadIdx.x;
  if (i < 196608) {
    float4 v = ((const float4*)wi)[i];
    union { bf16 h[4]; uint2 u; } p;
    p.h[0] = __float2bfloat16(v.x); p.h[1] = __float2bfloat16(v.y);
    p.h[2] = __float2bfloat16(v.z); p.h[3] = __float2bfloat16(v.w);
    *(uint2*)&wib[(size_t)i * 4] = p.u;
  } else {
    int j = i - 196608;                   // 65536 float4s of w_out [512][512]
    float4 v = ((const float4*)wo)[j];
    int elem = j * 4;
    int co = elem >> 9, c = elem & 511;   // 4 consecutive c
    union { bf16 h[4]; uint2 u; } p;
    p.h[0] = __float2bfloat16(v.x); p.h[1] = __float2bfloat16(v.y);
    p.h[2] = __float2bfloat16(v.z); p.h[3] = __float2bfloat16(v.w);
    int chh = co >> 4, col_ = co & 15, kc = c >> 5, cc = c & 31;
    *(uint2*)(wobf + (((chh * 16 + kc) << 10) + col_ * 64 + cc * 2)) = p.u;
  }
}

// ---------------- GroupNorm -> xn token-major bf16 [b][hw][c] ----------------
__global__ __launch_bounds__(256) void gn_kernel(
    const float* __restrict__ x, const float* __restrict__ gamma,
    const float* __restrict__ beta, bf16* __restrict__ xn) {
  int blk = blockIdx.x;
  int b = blk >> 5, g = blk & 31;
  size_t base = ((size_t)(b * NC + g * 16)) * HW;
  const float4* src4 = (const float4*)(x + base);
  int t = threadIdx.x;
  float s = 0.f, ss = 0.f;
  float4 v[16];
#pragma unroll
  for (int i = 0; i < 16; ++i) {
    v[i] = src4[t + i * 256];
    s  += v[i].x + v[i].y + v[i].z + v[i].w;
    ss += v[i].x * v[i].x + v[i].y * v[i].y + v[i].z * v[i].z + v[i].w * v[i].w;
  }
  __shared__ float red[256];
  red[t] = s; __syncthreads();
  for (int o = 128; o > 0; o >>= 1) { if (t < o) red[t] += red[t + o]; __syncthreads(); }
  float mean = red[0] * (1.f / 16384.f);
  __syncthreads();
  red[t] = ss; __syncthreads();
  for (int o = 128; o > 0; o >>= 1) { if (t < o) red[t] += red[t + o]; __syncthreads(); }
  float var = red[0] * (1.f / 16384.f) - mean * mean;
  float rstd = rsqrtf(var + EPSV);

  __shared__ bf16 sm[16][1032];
#pragma unroll
  for (int i = 0; i < 16; ++i) {
    int idx = t + i * 256;
    int c = idx >> 8;
    int hw4 = (idx & 255) * 4;
    float gm = gamma[g * 16 + c], bt = beta[g * 16 + c];
    union { bf16 h[4]; uint2 u; } p;
    p.h[0] = __float2bfloat16((v[i].x - mean) * rstd * gm + bt);
    p.h[1] = __float2bfloat16((v[i].y - mean) * rstd * gm + bt);
    p.h[2] = __float2bfloat16((v[i].z - mean) * rstd * gm + bt);
    p.h[3] = __float2bfloat16((v[i].w - mean) * rstd * gm + bt);
    *(uint2*)&sm[c][hw4] = p.u;
  }
  __syncthreads();
  bf16* dst = xn + (size_t)b * HW * NC + g * 16;
#pragma unroll
  for (int it = 0; it < 8; ++it) {
    int u = it * 256 + t;
    int hw = u >> 1;
    int c8 = (u & 1) * 8;
    union { bf16 h[8]; uint4 q; } p;
#pragma unroll
    for (int j = 0; j < 8; ++j) p.h[j] = sm[c8 + j][hw];
    *(uint4*)&dst[(size_t)hw * NC + c8] = p.q;
  }
}

// ---------------- merged QKV projection GEMM (one launch) ----------------
// C[M=1536][N=1024tok] = wib[1536][512] * xn^T, store per m0-range:
//   m0<512: qtok [tok][512] transposed;  <1024: K-frag [jflat 64][kw 16][1KB];
//   else:   V-frag [tile 8][chh 32][ks 4][1KB]. Block-uniform dispatch.
__global__ __launch_bounds__(256) void qkv_gemm(
    const bf16* __restrict__ wib, const bf16* __restrict__ xn,
    const float* __restrict__ bias,
    bf16* __restrict__ qtok, char* __restrict__ kfrag, char* __restrict__ vfrag) {
  __shared__ bf16 sT[2][128][32];
  int z = blockIdx.z;
  const bf16* Bb = xn + (size_t)z * (512 * 1024);
  int n0 = blockIdx.x * 128, m0 = blockIdx.y * 128;
  int t = threadIdx.x;
  int l = t & 63, w = t >> 6;
  int wm = w >> 1, wn = w & 1;

  int srow = t >> 2;
  int scol = (t & 3) * 8;

  f32x4 acc[4][4] = {};

  const bf16* ga0 = wib + (size_t)(m0 + srow) * 512 + scol;
  const bf16* gb0 = Bb + (size_t)(n0 + srow) * 512 + scol;

  for (int k0 = 0; k0 < 512; k0 += 32) {
    gload16(ga0 + k0, &sT[0][srow][scol]);
    gload16(ga0 + (size_t)64 * 512 + k0, &sT[0][64 + srow][scol]);
    gload16(gb0 + k0, &sT[1][srow][scol]);
    gload16(gb0 + (size_t)64 * 512 + k0, &sT[1][64 + srow][scol]);
    __syncthreads();
    bf16x8 af[4], bfr[4];
    int kc = (l >> 4) * 8;
    int ra = wm * 64 + (l & 15);
    int rb = wn * 64 + (l & 15);
#pragma unroll
    for (int i = 0; i < 4; ++i) {
      af[i]  = *(const bf16x8*)&sT[0][ra + i * 16][kc];
      bfr[i] = *(const bf16x8*)&sT[1][rb + i * 16][kc];
    }
#pragma unroll
    for (int i = 0; i < 4; ++i)
#pragma unroll
      for (int j = 0; j < 4; ++j)
        acc[i][j] = __builtin_amdgcn_mfma_f32_16x16x32_bf16(af[i], bfr[j], acc[i][j], 0, 0, 0);
    __syncthreads();
  }

  int rbase = (l >> 4) * 4;
#pragma unroll
  for (int i = 0; i < 4; ++i) {
    int row = m0 + wm * 64 + i * 16 + rbase;    // 0..1535
    float4 bv = *(const float4*)&bias[row];
    float bb[4] = {bv.x, bv.y, bv.z, bv.w};
#pragma unroll
    for (int j = 0; j < 4; ++j) {
      int col = n0 + wn * 64 + j * 16 + (l & 15);
      if (m0 < 512) {
        bf16* C = qtok + (size_t)z * 524288;
        union { bf16 h[4]; uint2 u; } p;
#pragma unroll
        for (int r = 0; r < 4; ++r) p.h[r] = __float2bfloat16(acc[i][j][r] + bb[r]);
        *(uint2*)&C[(size_t)col * 512 + row] = p.u;
      } else if (m0 < 1024) {
        char* C = kfrag + (size_t)z * 1048576;
        int rk = row - 512;
        int jflat = col >> 4, j_lo = col & 15;
        int kw = rk >> 5, cc = rk & 31;
        union { bf16 h[4]; uint2 u; } p;
#pragma unroll
        for (int r = 0; r < 4; ++r) p.h[r] = __float2bfloat16(acc[i][j][r] + bb[r]);
        *(uint2*)(C + (((size_t)(jflat * 16 + kw)) << 10) + j_lo * 64 + cc * 2) = p.u;
      } else {
        char* C = vfrag + (size_t)z * 1048576;
        int rv = row - 1024;
        int tile = col >> 7, jj = col & 127;
        int ks = jj >> 5, jc = jj & 31;
#pragma unroll
        for (int r = 0; r < 4; ++r) {
          int ch = rv + r;
          int chh = ch >> 4, chl = ch & 15;
          *(bf16*)(C + (((tile * 32 + chh) * 4 + ks) << 10)
                     + chl * 64 + jc * 2) = __float2bfloat16(acc[i][j][r] + bb[r]);
        }
      }
    }
  }
}

// ---------------- fused flash attention + out-projection ----------------
// grid: 256 wg (QBLK=64), 512 threads (8 waves). KVBLK=256, 4 KV tiles.
// Wave owns 32 j (2 j-groups) per tile: each Q fragment read from LDS feeds
// TWO MFMAs. K,V,W direct from L2 in fragment-linear layout (1KB coalesced
// wave reads, XCD-pinned). LDS 96KB: Qs 64KB + Ps 32KB ([ni 4][js 8][1KB]).
__global__ __launch_bounds__(512, 1) void flash_kernel(
    const bf16* __restrict__ qtok, const bf16* __restrict__ kfrag,
    const bf16* __restrict__ vfrag, const bf16* __restrict__ wfrag,
    const float* __restrict__ b_out, const float* __restrict__ x,
    float* __restrict__ out) {
  __shared__ char lds[98304];
  char* Qs = lds;                        // 64KB: [ni 4][ks 16][i_lo 16][64B]
  char* Ps = lds + 65536;                // 32KB: [ni 4][js 8][i_lo 16][64B]
  float* redl = (float*)(lds + 65536);   // epilogue overlay (2KB, Ps dead)

  int id = blockIdx.x;
  int xcd = id & 7, rest = id >> 3;
  int q = rest & 15, bh = rest >> 4;
  int b = xcd + bh * 8;                  // batch -> fixed XCD (K/V L2 locality)
  int i0 = q * 64;

  const char* qC = (const char*)qtok + (size_t)b * 1048576;   // [1024 tok][512]
  const char* kC = (const char*)kfrag + (size_t)b * 1048576;  // frag layout
  const char* vC = (const char*)vfrag + (size_t)b * 1048576;  // frag layout
  const char* wC = (const char*)wfrag;                        // frag layout

  int t = threadIdx.x, l = t & 63, w = t >> 6;
  int l15 = l & 15, lq = l >> 4;
  int fofs = l15 * 64 + lq * 16;         // fragment byte offset (row l15, lq)
  int chb = w * 64;

  // ---- prologue: stage Q subtiled
#pragma unroll
  for (int it = 0; it < 8; ++it) {
    int A = it * 8192 + t * 16;
    int ih2 = A >> 14, ks = (A >> 10) & 15, ilo = (A >> 6) & 15, cb = A & 63;
    gload16(qC + (size_t)(i0 + ih2 * 16 + ilo) * 1024 + ks * 64 + cb, Qs + A);
  }

  float lacc[4] = {0.f, 0.f, 0.f, 0.f};
  f32x4 o[4][4] = {};                        // [mi: ch frag][ni: i frag]
  const float scl = 0.044194173824159216f;   // 1/sqrt(512)

  __syncthreads();   // Q staged

  for (int tile = 0; tile < 4; ++tile) {
    // V prefetch half A: js 0..3 (f = tile*8+js), consumed after P barrier
    bf16x8 vfA[4][4];
#pragma unroll
    for (int js = 0; js < 4; ++js)
#pragma unroll
      for (int mi = 0; mi < 4; ++mi) {
        int f = tile * 8 + js;
        vfA[js][mi] = *(const bf16x8*)(vC
            + (((size_t)(((f >> 2) * 32 + (w * 4 + mi)) * 4 + (f & 3))) << 10) + fofs);
      }
    // ---- QK^T: S^T[32 j][64 i] per wave (2 j-groups share each Q read)
    f32x4 s0[4] = {}, s1[4] = {};
#pragma unroll
    for (int kw = 0; kw < 16; ++kw) {
      int jf0 = tile * 16 + w * 2;
      bf16x8 kf0 = *(const bf16x8*)(kC + (((size_t)(jf0 * 16 + kw)) << 10) + fofs);
      bf16x8 kf1 = *(const bf16x8*)(kC + (((size_t)((jf0 + 1) * 16 + kw)) << 10) + fofs);
#pragma unroll
      for (int ni = 0; ni < 4; ++ni) {
        bf16x8 qf = *(const bf16x8*)(Qs + ni * 16384 + kw * 1024 + fofs);
        s0[ni] = __builtin_amdgcn_mfma_f32_16x16x32_bf16(kf0, qf, s0[ni], 0, 0, 0);
        s1[ni] = __builtin_amdgcn_mfma_f32_16x16x32_bf16(kf1, qf, s1[ni], 0, 0, 0);
      }
    }
    // ---- P = exp(s*scl), pack into Ps[ni][js=w]; j_in_32 = jg*16 + lq*4 + r
#pragma unroll
    for (int ni = 0; ni < 4; ++ni) {
#pragma unroll
      for (int jg = 0; jg < 2; ++jg) {
        const f32x4& sv = jg ? s1[ni] : s0[ni];
        float p0 = __expf(sv[0] * scl);
        float p1 = __expf(sv[1] * scl);
        float p2 = __expf(sv[2] * scl);
        float p3 = __expf(sv[3] * scl);
        lacc[ni] += p0 + p1 + p2 + p3;
        union { bf16 h[4]; uint64_t u; } pk;
        pk.h[0] = __float2bfloat16(p0); pk.h[1] = __float2bfloat16(p1);
        pk.h[2] = __float2bfloat16(p2); pk.h[3] = __float2bfloat16(p3);
        *(uint64_t*)(Ps + ni * 8192 + w * 1024 + l15 * 64 + jg * 32 + lq * 8) = pk.u;
      }
    }
    __syncthreads();   // P ready
    // V prefetch half B: js 4..7 (loads fly under PV of half A)
    bf16x8 vfB[4][4];
#pragma unroll
    for (int js = 0; js < 4; ++js)
#pragma unroll
      for (int mi = 0; mi < 4; ++mi) {
        int f = tile * 8 + 4 + js;
        vfB[js][mi] = *(const bf16x8*)(vC
            + (((size_t)(((f >> 2) * 32 + (w * 4 + mi)) * 4 + (f & 3))) << 10) + fofs);
      }
    // ---- PV: O^T[64 ch][64 i] += V^T x P
#pragma unroll
    for (int js = 0; js < 4; ++js)
#pragma unroll
      for (int ni = 0; ni < 4; ++ni) {
        bf16x8 pf = *(const bf16x8*)(Ps + ni * 8192 + js * 1024 + fofs);
#pragma unroll
        for (int mi = 0; mi < 4; ++mi)
          o[mi][ni] = __builtin_amdgcn_mfma_f32_16x16x32_bf16(vfA[js][mi], pf, o[mi][ni], 0, 0, 0);
      }
#pragma unroll
    for (int js = 0; js < 4; ++js)
#pragma unroll
      for (int ni = 0; ni < 4; ++ni) {
        bf16x8 pf = *(const bf16x8*)(Ps + ni * 8192 + (4 + js) * 1024 + fofs);
#pragma unroll
        for (int mi = 0; mi < 4; ++mi)
          o[mi][ni] = __builtin_amdgcn_mfma_f32_16x16x32_bf16(vfB[js][mi], pf, o[mi][ni], 0, 0, 0);
      }
    __syncthreads();   // PV done -> Ps free for next tile
  }

  // ---- row-sum combine (redl overlays dead Ps)
#pragma unroll
  for (int ni = 0; ni < 4; ++ni) {
    float v = lacc[ni];
    v += __shfl_xor(v, 16);
    v += __shfl_xor(v, 32);
    if (l < 16) redl[w * 64 + ni * 16 + l] = v;
  }
  __syncthreads();
  float linv[4];
#pragma unroll
  for (int ni = 0; ni < 4; ++ni) {
    int i = ni * 16 + l15;
    float v = redl[i];
#pragma unroll
    for (int w2 = 1; w2 < 8; ++w2) v += redl[w2 * 64 + i];
    linv[ni] = 1.f / v;
  }
  // normalized O -> ao_lds subtiled [ni 4][kc 16][i_lo 16][64B] over dead Qs
#pragma unroll
  for (int mi = 0; mi < 4; ++mi)
#pragma unroll
    for (int ni = 0; ni < 4; ++ni) {
      union { bf16 h[4]; uint64_t u; } pk;
#pragma unroll
      for (int r = 0; r < 4; ++r)
        pk.h[r] = __float2bfloat16(o[mi][ni][r] * linv[ni]);
      int dst = ni * 16384 + (w * 2 + (mi >> 1)) * 1024 + l15 * 64
              + (mi & 1) * 32 + lq * 8;
      *(uint64_t*)(Qs + dst) = pk.u;
    }
  __syncthreads();  // ao_lds ready

  // ---- out-projection: W fragments direct from L2; no barriers in loop
  f32x4 acc2[4][4] = {};
#pragma unroll
  for (int kc = 0; kc < 16; ++kc) {
    bf16x8 wf[4];
#pragma unroll
    for (int mi = 0; mi < 4; ++mi)
      wf[mi] = *(const bf16x8*)(wC + (((size_t)(w * 4 + mi) * 16 + kc) << 10) + fofs);
#pragma unroll
    for (int ni = 0; ni < 4; ++ni) {
      bf16x8 pf = *(const bf16x8*)(Qs + ni * 16384 + kc * 1024 + fofs);
#pragma unroll
      for (int mi = 0; mi < 4; ++mi)
        acc2[mi][ni] = __builtin_amdgcn_mfma_f32_16x16x32_bf16(wf[mi], pf, acc2[mi][ni], 0, 0, 0);
    }
  }

  // epilogue: + bias + residual, store fp32 out[b][co][i0+i]
  const float* xb = x + (size_t)b * 524288;
  float* ob = out + (size_t)b * 524288;
#pragma unroll
  for (int mi = 0; mi < 4; ++mi) {
    int cbase = chb + mi * 16 + lq * 4;
    float4 bv = *(const float4*)&b_out[cbase];
    float bb[4] = {bv.x, bv.y, bv.z, bv.w};
#pragma unroll
    for (int ni = 0; ni < 4; ++ni) {
      int i = i0 + ni * 16 + l15;
#pragma unroll
      for (int r = 0; r < 4; ++r) {
        size_t off = (size_t)(cbase + r) * 1024 + i;
        ob[off] = acc2[mi][ni][r] + bb[r] + xb[off];
      }
    }
  }
}

extern "C" void kernel_launch(void* const* d_in, const int* in_sizes, int n_in,
                              void* d_out, int out_size, void* d_ws, size_t ws_size,
                              hipStream_t stream) {
  const float* x     = (const float*)d_in[0];
  const float* gamma = (const float*)d_in[1];
  const float* beta  = (const float*)d_in[2];
  const float* w_in  = (const float*)d_in[3];
  const float* b_in  = (const float*)d_in[4];
  const float* w_out = (const float*)d_in[5];
  const float* b_out = (const float*)d_in[6];
  float* out = (float*)d_out;

  char* w = (char*)d_ws;
  bf16* xn    = (bf16*)w;                              // 16 MB token-major
  bf16* qtok  = (bf16*)(w + ((size_t)16 << 20));       // 16 MB [b][tok][512]
  bf16* kfrag = (bf16*)(w + ((size_t)32 << 20));       // 16 MB fragment layout
  bf16* vfrag = (bf16*)(w + ((size_t)48 << 20));       // 16 MB fragment layout
  bf16* wib   = (bf16*)(w + ((size_t)64 << 20));       // 1.5 MB
  char* wobf  = (char*)(w + ((size_t)64 << 20) + ((size_t)3 << 19));  // 0.5 MB

  cvt_w_kernel<<<1024, 256, 0, stream>>>(w_in, w_out, wib, wobf);
  gn_kernel<<<NB * 32, 256, 0, stream>>>(x, gamma, beta, xn);

  // merged q/k/v projection: one launch, store-mode by m0 range
  qkv_gemm<<<dim3(8, 12, NB), 256, 0, stream>>>(
      wib, xn, b_in, qtok, (char*)kfrag, (char*)vfrag);

  // fused attention + out projection + residual
  flash_kernel<<<256, 512, 0, stream>>>(qtok, kfrag, vfrag, (const bf16*)wobf,
                                        b_out, x, out);
}